// Round 3
// baseline (1881.067 us; speedup 1.0000x reference)
//
#include <hip/hip_runtime.h>
#include <math.h>

// CapsNet dynamic routing, fp32.
// x: [B=64, N=1152, Din=8], W: [C=128, N=1152, Din=8, Dout=16]
// out: [B=64, C=128, Dout=16]  (normalized per batch at the end)
//
// R2 -> R3: counters showed ~88% stall, ~1 block/CU resident (Occupancy 18%),
// VALU-issue only ~160us of 1250us. Lever: BT=2 (halves W traffic and halves
// sequential block rounds per CU) WITH a 256-VGPR budget (launch_bounds(384,2))
// so we don't repeat R1's spill. Divides -> fast rcp (absmax headroom 100x).

constexpr int NCAP = 1152;
constexpr int DIN  = 8;
constexpr int DOUT = 16;
constexpr int NCLS = 128;
constexpr int NB   = 64;

constexpr int BLK   = 384;          // 6 waves
constexpr int NWAVE = BLK / 64;
constexpr int NPT   = NCAP / BLK;   // 3 capsules per thread
constexpr int BT    = 2;            // batches per block (W reuse)
constexpr int ITERS = 3;

__device__ __forceinline__ float fast_rcp(float x) {
    return __builtin_amdgcn_rcpf(x);
}

__global__ __launch_bounds__(BLK, 2) void caps_kernel(const float* __restrict__ x,
                                                      const float* __restrict__ W,
                                                      float* __restrict__ out) {
    const int tid  = threadIdx.x;
    const int lane = tid & 63;
    const int wv   = tid >> 6;

    // XCD-aware mapping: the 32 blocks sharing class c land on one XCD so the
    // 576 KB W[c] panel stays L2-resident; b-major within a class.
    const int orig = blockIdx.x;              // 0..4095
    const int xcd  = orig & 7;
    const int rest = orig >> 3;               // 0..511
    const int c    = xcd * 16 + (rest >> 5);  // 0..127
    const int b0   = (rest & 31) * BT;        // 0..62

    __shared__ float lds_vec[NWAVE][BT * DOUT];
    __shared__ float lds_sc[NWAVE][BT];

    // ---- u_hat[c, b0+bt, n, :] for this thread's NPT capsules, in registers
    float u[BT][NPT][DOUT];

#pragma unroll
    for (int k = 0; k < NPT; ++k) {
        const int n = tid + k * BLK;
        float xs[BT][DIN];
#pragma unroll
        for (int bt = 0; bt < BT; ++bt) {
            const float4* xp = reinterpret_cast<const float4*>(
                x + ((size_t)(b0 + bt) * NCAP + n) * DIN);
            float4 xa = xp[0];
            float4 xb = xp[1];
            float sq = xa.x*xa.x + xa.y*xa.y + xa.z*xa.z + xa.w*xa.w
                     + xb.x*xb.x + xb.y*xb.y + xb.z*xb.z + xb.w*xb.w;
            // squash scale: sq/(1+sq)/sqrt(sq)
            float sc = sq * fast_rcp((1.0f + sq) * sqrtf(sq));
            xs[bt][0] = xa.x * sc; xs[bt][1] = xa.y * sc;
            xs[bt][2] = xa.z * sc; xs[bt][3] = xa.w * sc;
            xs[bt][4] = xb.x * sc; xs[bt][5] = xb.y * sc;
            xs[bt][6] = xb.z * sc; xs[bt][7] = xb.w * sc;
        }
#pragma unroll
        for (int bt = 0; bt < BT; ++bt)
#pragma unroll
            for (int o = 0; o < DOUT; ++o) u[bt][k][o] = 0.0f;

        const float4* wp = reinterpret_cast<const float4*>(
            W + ((size_t)c * NCAP + n) * (DIN * DOUT));
#pragma unroll
        for (int i = 0; i < DIN; ++i) {
            float4 w0 = wp[i*4+0], w1 = wp[i*4+1], w2 = wp[i*4+2], w3 = wp[i*4+3];
            const float wrow[DOUT] = {w0.x,w0.y,w0.z,w0.w, w1.x,w1.y,w1.z,w1.w,
                                      w2.x,w2.y,w2.z,w2.w, w3.x,w3.y,w3.z,w3.w};
#pragma unroll
            for (int bt = 0; bt < BT; ++bt) {
                const float xv = xs[bt][i];
#pragma unroll
                for (int o = 0; o < DOUT; ++o)
                    u[bt][k][o] = fmaf(xv, wrow[o], u[bt][k][o]);
            }
        }
    }

    // ---- dynamic routing, all in registers + tiny LDS reductions
    float brt[BT][NPT];
#pragma unroll
    for (int bt = 0; bt < BT; ++bt)
#pragma unroll
        for (int k = 0; k < NPT; ++k) brt[bt][k] = 0.0f;

    float v[BT][DOUT];

    for (int it = 0; it < ITERS; ++it) {
        // -- block max over N (softmax stability)
        float mx[BT];
#pragma unroll
        for (int bt = 0; bt < BT; ++bt) {
            float m = brt[bt][0];
#pragma unroll
            for (int k = 1; k < NPT; ++k) m = fmaxf(m, brt[bt][k]);
            mx[bt] = m;
        }
#pragma unroll
        for (int off = 1; off < 64; off <<= 1)
#pragma unroll
            for (int bt = 0; bt < BT; ++bt)
                mx[bt] = fmaxf(mx[bt], __shfl_xor(mx[bt], off));
        __syncthreads();
        if (lane == 0)
#pragma unroll
            for (int bt = 0; bt < BT; ++bt) lds_sc[wv][bt] = mx[bt];
        __syncthreads();
#pragma unroll
        for (int bt = 0; bt < BT; ++bt) {
            float m = lds_sc[0][bt];
#pragma unroll
            for (int w2 = 1; w2 < NWAVE; ++w2) m = fmaxf(m, lds_sc[w2][bt]);
            mx[bt] = m;
        }

        // -- exp + block sum
        float e[BT][NPT];
        float sm[BT];
#pragma unroll
        for (int bt = 0; bt < BT; ++bt) {
            float s = 0.0f;
#pragma unroll
            for (int k = 0; k < NPT; ++k) {
                e[bt][k] = __expf(brt[bt][k] - mx[bt]);
                s += e[bt][k];
            }
            sm[bt] = s;
        }
#pragma unroll
        for (int off = 1; off < 64; off <<= 1)
#pragma unroll
            for (int bt = 0; bt < BT; ++bt) sm[bt] += __shfl_xor(sm[bt], off);
        __syncthreads();
        if (lane == 0)
#pragma unroll
            for (int bt = 0; bt < BT; ++bt) lds_sc[wv][bt] = sm[bt];
        __syncthreads();
#pragma unroll
        for (int bt = 0; bt < BT; ++bt) {
            float s = 0.0f;
#pragma unroll
            for (int w2 = 0; w2 < NWAVE; ++w2) s += lds_sc[w2][bt];
            sm[bt] = s;
        }

        // -- s[o] = (sum_n e_n * u[n][o]) / sum_n e_n, then squash
        float sp[BT][DOUT];
#pragma unroll
        for (int bt = 0; bt < BT; ++bt)
#pragma unroll
            for (int o = 0; o < DOUT; ++o) sp[bt][o] = 0.0f;
#pragma unroll
        for (int bt = 0; bt < BT; ++bt)
#pragma unroll
            for (int k = 0; k < NPT; ++k) {
                const float ek = e[bt][k];
#pragma unroll
                for (int o = 0; o < DOUT; ++o)
                    sp[bt][o] = fmaf(ek, u[bt][k][o], sp[bt][o]);
            }
#pragma unroll
        for (int off = 1; off < 64; off <<= 1)
#pragma unroll
            for (int bt = 0; bt < BT; ++bt)
#pragma unroll
                for (int o = 0; o < DOUT; ++o)
                    sp[bt][o] += __shfl_xor(sp[bt][o], off);
        __syncthreads();
        if (lane == 0)
#pragma unroll
            for (int bt = 0; bt < BT; ++bt)
#pragma unroll
                for (int o = 0; o < DOUT; ++o) lds_vec[wv][bt*DOUT+o] = sp[bt][o];
        __syncthreads();
#pragma unroll
        for (int bt = 0; bt < BT; ++bt) {
            float sq = 0.0f;
            float sv[DOUT];
            const float rs = fast_rcp(sm[bt]);
#pragma unroll
            for (int o = 0; o < DOUT; ++o) {
                float s = 0.0f;
#pragma unroll
                for (int w2 = 0; w2 < NWAVE; ++w2) s += lds_vec[w2][bt*DOUT+o];
                s *= rs;
                sv[o] = s;
                sq = fmaf(s, s, sq);
            }
            const float scale = sq * fast_rcp((1.0f + sq) * sqrtf(sq));
#pragma unroll
            for (int o = 0; o < DOUT; ++o) v[bt][o] = sv[o] * scale;
        }

        // -- agreement update (not on last iter)
        if (it < ITERS - 1) {
#pragma unroll
            for (int bt = 0; bt < BT; ++bt)
#pragma unroll
                for (int k = 0; k < NPT; ++k) {
                    float a = 0.0f;
#pragma unroll
                    for (int o = 0; o < DOUT; ++o)
                        a = fmaf(u[bt][k][o], v[bt][o], a);
                    brt[bt][k] += a;
                }
        }
    }

    // ---- leaky_relu(v)^2, write pre-normalized output
    if (tid < BT * DOUT) {
        const int bt = tid >> 4;
        const int o  = tid & 15;
        float val = v[bt][o];
        float l = val > 0.0f ? val : 0.01f * val;
        out[((size_t)(b0 + bt) * NCLS + c) * DOUT + o] = l * l;
    }
}

// per-batch normalization of out[b, :, :] (2048 floats per b), in place
__global__ __launch_bounds__(256) void norm_kernel(float* __restrict__ out) {
    const int b   = blockIdx.x;
    const int tid = threadIdx.x;
    float4* p = reinterpret_cast<float4*>(out + (size_t)b * NCLS * DOUT);
    float4 a0 = p[tid];
    float4 a1 = p[tid + 256];
    float s = a0.x + a0.y + a0.z + a0.w + a1.x + a1.y + a1.z + a1.w;
#pragma unroll
    for (int off = 1; off < 64; off <<= 1) s += __shfl_xor(s, off);
    __shared__ float ws[4];
    if ((tid & 63) == 0) ws[tid >> 6] = s;
    __syncthreads();
    const float inv = __builtin_amdgcn_rcpf(ws[0] + ws[1] + ws[2] + ws[3]);
    a0.x *= inv; a0.y *= inv; a0.z *= inv; a0.w *= inv;
    a1.x *= inv; a1.y *= inv; a1.z *= inv; a1.w *= inv;
    p[tid]       = a0;
    p[tid + 256] = a1;
}

extern "C" void kernel_launch(void* const* d_in, const int* in_sizes, int n_in,
                              void* d_out, int out_size, void* d_ws, size_t ws_size,
                              hipStream_t stream) {
    const float* x = (const float*)d_in[0];
    const float* W = (const float*)d_in[1];
    float* out = (float*)d_out;
    hipLaunchKernelGGL(caps_kernel, dim3(NCLS * (NB / BT)), dim3(BLK), 0, stream,
                       x, W, out);
    hipLaunchKernelGGL(norm_kernel, dim3(NB), dim3(256), 0, stream, out);
}

// Round 4
// 461.744 us; speedup vs baseline: 4.0738x; 4.0738x over previous
//
#include <hip/hip_runtime.h>
#include <math.h>

// CapsNet dynamic routing, fp32 — streaming-sweep reformulation.
//
// Key identity: b after iter k is u_n . (v1+...+v_{k-1}), so routing = 3
// streaming passes over n, recomputing u_n from W each pass and keeping only
// (Z, S[16]) per (c,b). No u_hat storage -> no register wall, W read once per
// sweep (75.5 MB). No max-subtraction needed in softmax: |b| <= ~48, exp fp32-safe.
//
// x: [B=64, N=1152, Din=8], W: [C=128, N=1152, Din=8, Dout=16]
// out: [B=64, C=128, Dout=16]

constexpr int NCAP = 1152;
constexpr int DIN  = 8;
constexpr int DOUT = 16;
constexpr int NCLS = 128;
constexpr int NB   = 64;

constexpr int CH        = 4;                  // n-chunks (blocks) per class
constexpr int NW        = 8;                  // waves per sweep block
constexpr int SWEEP_BLK = NW * 64;            // 512 threads
constexpr int NPW       = NCAP / (CH * NW);   // 36 n per wave
constexpr int NPC       = NCAP / CH;          // 288 n per block

// ws layout (float offsets)
constexpr size_t XS_OFF = 0;
constexpr size_t XS_SZ  = (size_t)NCAP * NB * DIN;               // 589,824
constexpr size_t P1_OFF = XS_OFF + XS_SZ;
constexpr size_t P1_SZ  = (size_t)NCLS * CH * DOUT * NB;         // 524,288
constexpr size_t P2_OFF = P1_OFF + P1_SZ;
constexpr size_t P23_SZ = (size_t)NCLS * CH * (DOUT + 1) * NB;   // 557,056
constexpr size_t P3_OFF = P2_OFF + P23_SZ;                       // total ~8.9 MB

// ---- prep: squash(x) and transpose to xs[n][b][0..7] (per-lane float4-able)
__global__ __launch_bounds__(256) void prep_kernel(const float* __restrict__ x,
                                                   float* __restrict__ xs) {
    const int g = blockIdx.x * 256 + threadIdx.x;   // g = n*64 + b
    const int n = g >> 6;
    const int b = g & 63;
    const float4* xp = reinterpret_cast<const float4*>(x + ((size_t)b * NCAP + n) * DIN);
    float4 a = xp[0], c4 = xp[1];
    float sq = a.x*a.x + a.y*a.y + a.z*a.z + a.w*a.w
             + c4.x*c4.x + c4.y*c4.y + c4.z*c4.z + c4.w*c4.w;
    float sc = sq / ((1.0f + sq) * sqrtf(sq));
    float4 o0 = {a.x*sc,  a.y*sc,  a.z*sc,  a.w*sc};
    float4 o1 = {c4.x*sc, c4.y*sc, c4.z*sc, c4.w*sc};
    float4* op = reinterpret_cast<float4*>(xs + (size_t)g * DIN);
    op[0] = o0;
    op[1] = o1;
}

// ---- sweep k: one streaming pass over this block's n-range.
// PHASE 1: b=0 -> uniform coupling: S = sum_n u_n   (Z unused)
// PHASE 2: V = v1;       Z = sum exp(u.V), S = sum exp(u.V) u
// PHASE 3: V = v1+v2;    same accumulation, written to P3
template<int PHASE>
__global__ __launch_bounds__(SWEEP_BLK) void sweep_kernel(const float* __restrict__ xs,
                                                          const float* __restrict__ W,
                                                          float* __restrict__ ws) {
    const int c  = blockIdx.x >> 2;      // 0..127
    const int ch = blockIdx.x & 3;       // 0..3
    const int b  = threadIdx.x & 63;     // lane = batch
    const int w  = threadIdx.x >> 6;     // wave = n-subchunk

    float* P1 = ws + P1_OFF;
    float* P2 = ws + P2_OFF;
    float* P3 = ws + P3_OFF;

    // prologue: reconstruct V = sum of previous v's for (c, b)
    float V[DOUT];
    if (PHASE >= 2) {
        float sq = 0.f;
#pragma unroll
        for (int o = 0; o < DOUT; ++o) {
            float acc = 0.f;
#pragma unroll
            for (int k = 0; k < CH; ++k)
                acc += P1[(((size_t)c * CH + k) * DOUT + o) * NB + b];
            acc *= (1.0f / (float)NCAP);          // uniform c = 1/N
            V[o] = acc;
            sq += acc * acc;
        }
        const float sc = sq / ((1.0f + sq) * sqrtf(sq));
#pragma unroll
        for (int o = 0; o < DOUT; ++o) V[o] *= sc;   // V = v1
        if (PHASE == 3) {
            float Z2 = 0.f;
#pragma unroll
            for (int k = 0; k < CH; ++k)
                Z2 += P2[(((size_t)c * CH + k) * (DOUT + 1) + DOUT) * NB + b];
            const float rz = 1.0f / Z2;
            float s2[DOUT];
            float sq2 = 0.f;
#pragma unroll
            for (int o = 0; o < DOUT; ++o) {
                float acc = 0.f;
#pragma unroll
                for (int k = 0; k < CH; ++k)
                    acc += P2[(((size_t)c * CH + k) * (DOUT + 1) + o) * NB + b];
                acc *= rz;
                s2[o] = acc;
                sq2 += acc * acc;
            }
            const float sc2 = sq2 / ((1.0f + sq2) * sqrtf(sq2));
#pragma unroll
            for (int o = 0; o < DOUT; ++o) V[o] += s2[o] * sc2;  // V = v1+v2
        }
    }

    float S[DOUT];
#pragma unroll
    for (int o = 0; o < DOUT; ++o) S[o] = 0.f;
    float Z = 0.f;

    const int n0 = ch * NPC + w * NPW;
#pragma unroll 2
    for (int t = 0; t < NPW; ++t) {
        const int n = n0 + t;
        const float* wr = W + ((size_t)c * NCAP + n) * (DIN * DOUT);
        const float4* xp = reinterpret_cast<const float4*>(xs + ((size_t)n * NB + b) * DIN);
        float4 xa = xp[0], xb = xp[1];
        const float xv[DIN] = {xa.x, xa.y, xa.z, xa.w, xb.x, xb.y, xb.z, xb.w};
        if (PHASE == 1) {
#pragma unroll
            for (int i = 0; i < DIN; ++i) {
                const float4* wp = reinterpret_cast<const float4*>(wr + i * DOUT);
                float4 w0 = wp[0], w1 = wp[1], w2 = wp[2], w3 = wp[3];
                const float wv[DOUT] = {w0.x,w0.y,w0.z,w0.w, w1.x,w1.y,w1.z,w1.w,
                                        w2.x,w2.y,w2.z,w2.w, w3.x,w3.y,w3.z,w3.w};
#pragma unroll
                for (int o = 0; o < DOUT; ++o) S[o] = fmaf(xv[i], wv[o], S[o]);
            }
        } else {
            float u[DOUT];
#pragma unroll
            for (int o = 0; o < DOUT; ++o) u[o] = 0.f;
#pragma unroll
            for (int i = 0; i < DIN; ++i) {
                const float4* wp = reinterpret_cast<const float4*>(wr + i * DOUT);
                float4 w0 = wp[0], w1 = wp[1], w2 = wp[2], w3 = wp[3];
                const float wv[DOUT] = {w0.x,w0.y,w0.z,w0.w, w1.x,w1.y,w1.z,w1.w,
                                        w2.x,w2.y,w2.z,w2.w, w3.x,w3.y,w3.z,w3.w};
#pragma unroll
                for (int o = 0; o < DOUT; ++o) u[o] = fmaf(xv[i], wv[o], u[o]);
            }
            float bd = 0.f;
#pragma unroll
            for (int o = 0; o < DOUT; ++o) bd = fmaf(u[o], V[o], bd);
            const float g = __expf(bd);   // no max-sub needed: |bd| <= ~48
            Z += g;
#pragma unroll
            for (int o = 0; o < DOUT; ++o) S[o] = fmaf(g, u[o], S[o]);
        }
    }

    // cross-wave merge in LDS, then one global partial per (c,ch,slot,b)
    __shared__ float red[NW][DOUT + 1][NB];   // 34.8 KB
#pragma unroll
    for (int o = 0; o < DOUT; ++o) red[w][o][b] = S[o];
    red[w][DOUT][b] = Z;
    __syncthreads();
    for (int idx = threadIdx.x; idx < (DOUT + 1) * NB; idx += SWEEP_BLK) {
        const int slot = idx >> 6;
        const int bb   = idx & 63;
        float acc = 0.f;
#pragma unroll
        for (int k = 0; k < NW; ++k) acc += red[k][slot][bb];
        if (PHASE == 1) {
            if (slot < DOUT)
                P1[(((size_t)c * CH + ch) * DOUT + slot) * NB + bb] = acc;
        } else {
            float* P = (PHASE == 2) ? P2 : P3;
            P[(((size_t)c * CH + ch) * (DOUT + 1) + slot) * NB + bb] = acc;
        }
    }
}

// ---- final: merge P3 -> v3, leaky^2, per-batch normalize, write out[b,c,o]
__global__ __launch_bounds__(256) void final_kernel(const float* __restrict__ ws_ro,
                                                    float* __restrict__ out) {
    const float* P3 = ws_ro + P3_OFF;
    const int b    = blockIdx.x;
    const int tid  = threadIdx.x;
    const int c    = tid >> 1;
    const int half = tid & 1;   // 8 of 16 Dout elements each

    float Zt = 0.f;
#pragma unroll
    for (int k = 0; k < CH; ++k)
        Zt += P3[(((size_t)c * CH + k) * (DOUT + 1) + DOUT) * NB + b];
    const float rz = 1.0f / Zt;

    float s[8];
    float sqh = 0.f;
#pragma unroll
    for (int j = 0; j < 8; ++j) {
        const int o = half * 8 + j;
        float acc = 0.f;
#pragma unroll
        for (int k = 0; k < CH; ++k)
            acc += P3[(((size_t)c * CH + k) * (DOUT + 1) + o) * NB + b];
        acc *= rz;
        s[j] = acc;
        sqh += acc * acc;
    }
    const float sq = sqh + __shfl_xor(sqh, 1);
    const float sc = sq / ((1.0f + sq) * sqrtf(sq));

    float val[8];
    float ps = 0.f;
#pragma unroll
    for (int j = 0; j < 8; ++j) {
        const float v = s[j] * sc;
        const float l = v > 0.f ? v : 0.01f * v;
        val[j] = l * l;
        ps += val[j];
    }
#pragma unroll
    for (int off = 1; off < 64; off <<= 1) ps += __shfl_xor(ps, off);
    __shared__ float wsum[4];
    if ((tid & 63) == 0) wsum[tid >> 6] = ps;
    __syncthreads();
    const float inv = 1.0f / (wsum[0] + wsum[1] + wsum[2] + wsum[3]);
#pragma unroll
    for (int j = 0; j < 8; ++j)
        out[((size_t)b * NCLS + c) * DOUT + half * 8 + j] = val[j] * inv;
}

extern "C" void kernel_launch(void* const* d_in, const int* in_sizes, int n_in,
                              void* d_out, int out_size, void* d_ws, size_t ws_size,
                              hipStream_t stream) {
    const float* x = (const float*)d_in[0];
    const float* W = (const float*)d_in[1];
    float* out = (float*)d_out;
    float* ws  = (float*)d_ws;

    hipLaunchKernelGGL(prep_kernel, dim3(NCAP * NB / 256), dim3(256), 0, stream,
                       x, ws + XS_OFF);
    hipLaunchKernelGGL((sweep_kernel<1>), dim3(NCLS * CH), dim3(SWEEP_BLK), 0, stream,
                       ws + XS_OFF, W, ws);
    hipLaunchKernelGGL((sweep_kernel<2>), dim3(NCLS * CH), dim3(SWEEP_BLK), 0, stream,
                       ws + XS_OFF, W, ws);
    hipLaunchKernelGGL((sweep_kernel<3>), dim3(NCLS * CH), dim3(SWEEP_BLK), 0, stream,
                       ws + XS_OFF, W, ws);
    hipLaunchKernelGGL(final_kernel, dim3(NB), dim3(256), 0, stream, ws, out);
}

// Round 5
// 165.797 us; speedup vs baseline: 11.3456x; 2.7850x over previous
//
#include <hip/hip_runtime.h>
#include <math.h>

// CapsNet dynamic routing, fp32 — streaming sweeps with explicit software pipeline.
//
// R4 -> R5: R4 sweeps were latency-serialized (VGPR=36, VALUBusy 9.7%, 9x over
// the ~20us VALU floor). This version stages W rows into wave-private LDS via
// global_load_lds (16B width), issued 2 pairs (~1400cy) ahead with counted
// s_waitcnt vmcnt(N) (never 0 in steady state), xs prefetched 1 pair ahead into
// named registers. No __syncthreads in the hot loop (wave-private buffers).
//
// x: [B=64, N=1152, Din=8], W: [C=128, N=1152, Din=8, Dout=16]
// out: [B=64, C=128, Dout=16]

constexpr int NCAP = 1152;
constexpr int DIN  = 8;
constexpr int DOUT = 16;
constexpr int NCLS = 128;
constexpr int NB   = 64;

constexpr int CH        = 4;                  // n-chunks (blocks) per class
constexpr int NW        = 8;                  // waves per sweep block
constexpr int SWEEP_BLK = NW * 64;            // 512 threads
constexpr int NPC       = NCAP / CH;          // 288 rows per block
constexpr int NPW       = NPC / NW;           // 36 rows per wave
constexpr int NPAIRS    = NPW / 2;            // 18 row-pairs per wave
constexpr int STG       = 4096;               // per-wave staging: 4 bufs x 1KB
constexpr int ROW_BYTES = DIN * DOUT * 4;     // 512 B per W row

// ws layout (float offsets) — same as R4
constexpr size_t XS_OFF = 0;
constexpr size_t XS_SZ  = (size_t)NCAP * NB * DIN;               // 589,824
constexpr size_t P1_OFF = XS_OFF + XS_SZ;
constexpr size_t P1_SZ  = (size_t)NCLS * CH * DOUT * NB;         // 524,288
constexpr size_t P2_OFF = P1_OFF + P1_SZ;
constexpr size_t P23_SZ = (size_t)NCLS * CH * (DOUT + 1) * NB;   // 557,056
constexpr size_t P3_OFF = P2_OFF + P23_SZ;                       // total ~8.9 MB

#define WAITV(N) asm volatile("s_waitcnt vmcnt(" #N ")" ::: "memory")
#define SB() __builtin_amdgcn_sched_barrier(0)

// ---- prep: squash(x) and transpose to xs[n][b][0..7]
__global__ __launch_bounds__(256) void prep_kernel(const float* __restrict__ x,
                                                   float* __restrict__ xs) {
    const int g = blockIdx.x * 256 + threadIdx.x;   // g = n*64 + b
    const int n = g >> 6;
    const int b = g & 63;
    const float4* xp = reinterpret_cast<const float4*>(x + ((size_t)b * NCAP + n) * DIN);
    float4 a = xp[0], c4 = xp[1];
    float sq = a.x*a.x + a.y*a.y + a.z*a.z + a.w*a.w
             + c4.x*c4.x + c4.y*c4.y + c4.z*c4.z + c4.w*c4.w;
    float sc = sq / ((1.0f + sq) * sqrtf(sq));
    float4 o0 = {a.x*sc,  a.y*sc,  a.z*sc,  a.w*sc};
    float4 o1 = {c4.x*sc, c4.y*sc, c4.z*sc, c4.w*sc};
    float4* op = reinterpret_cast<float4*>(xs + (size_t)g * DIN);
    op[0] = o0;
    op[1] = o1;
}

// ---- sweep: one streaming pass over this block's n-range.
template<int PHASE>
__global__ __launch_bounds__(SWEEP_BLK, 2) void sweep_kernel(const float* __restrict__ xs,
                                                             const float* __restrict__ W,
                                                             float* __restrict__ ws) {
    const int c  = blockIdx.x >> 2;      // 0..127
    const int ch = blockIdx.x & 3;       // 0..3
    const int b  = threadIdx.x & 63;     // lane = batch
    const int w  = threadIdx.x >> 6;     // wave id

    // union: staging (8 waves x 4KB = 32KB) then reduction (8x17x64x4 = 34.8KB)
    __shared__ __align__(16) char smem[NW * (DOUT + 1) * NB * 4];

    float* P1 = ws + P1_OFF;
    float* P2 = ws + P2_OFF;
    float* P3 = ws + P3_OFF;

    // prologue: reconstruct V = sum of previous v's for (c, b)
    float V[DOUT];
    if (PHASE >= 2) {
        float sq = 0.f;
#pragma unroll
        for (int o = 0; o < DOUT; ++o) {
            float acc = 0.f;
#pragma unroll
            for (int k = 0; k < CH; ++k)
                acc += P1[(((size_t)c * CH + k) * DOUT + o) * NB + b];
            acc *= (1.0f / (float)NCAP);          // uniform c = 1/N
            V[o] = acc;
            sq += acc * acc;
        }
        const float sc = sq / ((1.0f + sq) * sqrtf(sq));
#pragma unroll
        for (int o = 0; o < DOUT; ++o) V[o] *= sc;   // V = v1
        if (PHASE == 3) {
            float Z2 = 0.f;
#pragma unroll
            for (int k = 0; k < CH; ++k)
                Z2 += P2[(((size_t)c * CH + k) * (DOUT + 1) + DOUT) * NB + b];
            const float rz = 1.0f / Z2;
            float s2[DOUT];
            float sq2 = 0.f;
#pragma unroll
            for (int o = 0; o < DOUT; ++o) {
                float acc = 0.f;
#pragma unroll
                for (int k = 0; k < CH; ++k)
                    acc += P2[(((size_t)c * CH + k) * (DOUT + 1) + o) * NB + b];
                acc *= rz;
                s2[o] = acc;
                sq2 += acc * acc;
            }
            const float sc2 = sq2 / ((1.0f + sq2) * sqrtf(sq2));
#pragma unroll
            for (int o = 0; o < DOUT; ++o) V[o] += s2[o] * sc2;  // V = v1+v2
        }
    }

    float S[DOUT];
#pragma unroll
    for (int o = 0; o < DOUT; ++o) S[o] = 0.f;
    float Z = 0.f;

    const int n0 = ch * NPC + w * NPW;
    const char* wsrc = (const char*)W + ((size_t)c * NCAP + n0) * ROW_BYTES;
    char* mybuf = smem + w * STG;

    // stage pair p (2 rows = 1KB): lane b loads 16B into mybuf[(p&3)*1024 + b*16]
    auto STAGE = [&](int p) {
        __builtin_amdgcn_global_load_lds(
            (const __attribute__((address_space(1))) void*)(wsrc + (size_t)p * 1024 + b * 16),
            (__attribute__((address_space(3))) void*)(mybuf + (p & 3) * 1024),
            16, 0, 0);
    };
    auto XROW = [&](int row, float4& xa, float4& xb) {
        const float4* xp = reinterpret_cast<const float4*>(
            xs + ((size_t)(n0 + row) * NB + b) * DIN);
        xa = xp[0];
        xb = xp[1];
    };
    auto ROW = [&](int p, int r, float4 xa, float4 xb) {
        const float4* wl = reinterpret_cast<const float4*>(mybuf + (p & 3) * 1024 + r * 512);
        const float xv[DIN] = {xa.x, xa.y, xa.z, xa.w, xb.x, xb.y, xb.z, xb.w};
        if (PHASE == 1) {
#pragma unroll
            for (int i = 0; i < DIN; ++i) {
                float4 q0 = wl[i*4+0], q1 = wl[i*4+1], q2 = wl[i*4+2], q3 = wl[i*4+3];
                const float xi = xv[i];
                S[ 0]=fmaf(xi,q0.x,S[ 0]); S[ 1]=fmaf(xi,q0.y,S[ 1]);
                S[ 2]=fmaf(xi,q0.z,S[ 2]); S[ 3]=fmaf(xi,q0.w,S[ 3]);
                S[ 4]=fmaf(xi,q1.x,S[ 4]); S[ 5]=fmaf(xi,q1.y,S[ 5]);
                S[ 6]=fmaf(xi,q1.z,S[ 6]); S[ 7]=fmaf(xi,q1.w,S[ 7]);
                S[ 8]=fmaf(xi,q2.x,S[ 8]); S[ 9]=fmaf(xi,q2.y,S[ 9]);
                S[10]=fmaf(xi,q2.z,S[10]); S[11]=fmaf(xi,q2.w,S[11]);
                S[12]=fmaf(xi,q3.x,S[12]); S[13]=fmaf(xi,q3.y,S[13]);
                S[14]=fmaf(xi,q3.z,S[14]); S[15]=fmaf(xi,q3.w,S[15]);
            }
        } else {
            float u[DOUT];
#pragma unroll
            for (int o = 0; o < DOUT; ++o) u[o] = 0.f;
#pragma unroll
            for (int i = 0; i < DIN; ++i) {
                float4 q0 = wl[i*4+0], q1 = wl[i*4+1], q2 = wl[i*4+2], q3 = wl[i*4+3];
                const float xi = xv[i];
                u[ 0]=fmaf(xi,q0.x,u[ 0]); u[ 1]=fmaf(xi,q0.y,u[ 1]);
                u[ 2]=fmaf(xi,q0.z,u[ 2]); u[ 3]=fmaf(xi,q0.w,u[ 3]);
                u[ 4]=fmaf(xi,q1.x,u[ 4]); u[ 5]=fmaf(xi,q1.y,u[ 5]);
                u[ 6]=fmaf(xi,q1.z,u[ 6]); u[ 7]=fmaf(xi,q1.w,u[ 7]);
                u[ 8]=fmaf(xi,q2.x,u[ 8]); u[ 9]=fmaf(xi,q2.y,u[ 9]);
                u[10]=fmaf(xi,q2.z,u[10]); u[11]=fmaf(xi,q2.w,u[11]);
                u[12]=fmaf(xi,q3.x,u[12]); u[13]=fmaf(xi,q3.y,u[13]);
                u[14]=fmaf(xi,q3.z,u[14]); u[15]=fmaf(xi,q3.w,u[15]);
            }
            float bd = 0.f;
#pragma unroll
            for (int o = 0; o < DOUT; ++o) bd = fmaf(u[o], V[o], bd);
            const float g = __expf(bd);   // |bd| <= ~48: fp32-safe, no max-sub
            Z += g;
#pragma unroll
            for (int o = 0; o < DOUT; ++o) S[o] = fmaf(g, u[o], S[o]);
        }
    };

    // ---- software pipeline: W staged 2 pairs ahead, xs 1 pair ahead.
    // FIFO per iter p: [STAGE(p+2)] [XROW(p+1) x4]. Steady-state wait = vmcnt(5).
    STAGE(0); SB();
    STAGE(1); SB();
    float4 ca0, ca1, cb0, cb1, na0, na1, nb0, nb1;
    XROW(0, ca0, ca1);
    XROW(1, cb0, cb1);
    SB();

#pragma unroll 1
    for (int p = 0; p < NPAIRS; ++p) {
        if (p + 2 < NPAIRS) STAGE(p + 2);
        SB();
        if (p + 1 < NPAIRS) {
            XROW(2 * (p + 1),     na0, na1);
            XROW(2 * (p + 1) + 1, nb0, nb1);
        }
        SB();
        if (p < NPAIRS - 2)       { WAITV(5); }
        else if (p == NPAIRS - 2) { WAITV(4); }
        else                      { WAITV(0); }
        SB();
        ROW(p, 0, ca0, ca1);
        ROW(p, 1, cb0, cb1);
        ca0 = na0; ca1 = na1; cb0 = nb0; cb1 = nb1;
    }

    // ---- cross-wave merge (reuse smem after all waves finish staging reads)
    __syncthreads();
    float (*red)[DOUT + 1][NB] = reinterpret_cast<float (*)[DOUT + 1][NB]>(smem);
#pragma unroll
    for (int o = 0; o < DOUT; ++o) red[w][o][b] = S[o];
    red[w][DOUT][b] = Z;
    __syncthreads();
    for (int idx = threadIdx.x; idx < (DOUT + 1) * NB; idx += SWEEP_BLK) {
        const int slot = idx >> 6;
        const int bb   = idx & 63;
        float acc = 0.f;
#pragma unroll
        for (int k = 0; k < NW; ++k) acc += red[k][slot][bb];
        if (PHASE == 1) {
            if (slot < DOUT)
                P1[(((size_t)c * CH + ch) * DOUT + slot) * NB + bb] = acc;
        } else {
            float* P = (PHASE == 2) ? P2 : P3;
            P[(((size_t)c * CH + ch) * (DOUT + 1) + slot) * NB + bb] = acc;
        }
    }
}

// ---- final: merge P3 -> v3, leaky^2, per-batch normalize, write out[b,c,o]
__global__ __launch_bounds__(256) void final_kernel(const float* __restrict__ ws_ro,
                                                    float* __restrict__ out) {
    const float* P3 = ws_ro + P3_OFF;
    const int b    = blockIdx.x;
    const int tid  = threadIdx.x;
    const int c    = tid >> 1;
    const int half = tid & 1;   // 8 of 16 Dout elements each

    float Zt = 0.f;
#pragma unroll
    for (int k = 0; k < CH; ++k)
        Zt += P3[(((size_t)c * CH + k) * (DOUT + 1) + DOUT) * NB + b];
    const float rz = 1.0f / Zt;

    float s[8];
    float sqh = 0.f;
#pragma unroll
    for (int j = 0; j < 8; ++j) {
        const int o = half * 8 + j;
        float acc = 0.f;
#pragma unroll
        for (int k = 0; k < CH; ++k)
            acc += P3[(((size_t)c * CH + k) * (DOUT + 1) + o) * NB + b];
        acc *= rz;
        s[j] = acc;
        sqh += acc * acc;
    }
    const float sq = sqh + __shfl_xor(sqh, 1);
    const float sc = sq / ((1.0f + sq) * sqrtf(sq));

    float val[8];
    float ps = 0.f;
#pragma unroll
    for (int j = 0; j < 8; ++j) {
        const float v = s[j] * sc;
        const float l = v > 0.f ? v : 0.01f * v;
        val[j] = l * l;
        ps += val[j];
    }
#pragma unroll
    for (int off = 1; off < 64; off <<= 1) ps += __shfl_xor(ps, off);
    __shared__ float wsum[4];
    if ((tid & 63) == 0) wsum[tid >> 6] = ps;
    __syncthreads();
    const float inv = 1.0f / (wsum[0] + wsum[1] + wsum[2] + wsum[3]);
#pragma unroll
    for (int j = 0; j < 8; ++j)
        out[((size_t)b * NCLS + c) * DOUT + half * 8 + j] = val[j] * inv;
}

extern "C" void kernel_launch(void* const* d_in, const int* in_sizes, int n_in,
                              void* d_out, int out_size, void* d_ws, size_t ws_size,
                              hipStream_t stream) {
    const float* x = (const float*)d_in[0];
    const float* W = (const float*)d_in[1];
    float* out = (float*)d_out;
    float* ws  = (float*)d_ws;

    hipLaunchKernelGGL(prep_kernel, dim3(NCAP * NB / 256), dim3(256), 0, stream,
                       x, ws + XS_OFF);
    hipLaunchKernelGGL((sweep_kernel<1>), dim3(NCLS * CH), dim3(SWEEP_BLK), 0, stream,
                       ws + XS_OFF, W, ws);
    hipLaunchKernelGGL((sweep_kernel<2>), dim3(NCLS * CH), dim3(SWEEP_BLK), 0, stream,
                       ws + XS_OFF, W, ws);
    hipLaunchKernelGGL((sweep_kernel<3>), dim3(NCLS * CH), dim3(SWEEP_BLK), 0, stream,
                       ws + XS_OFF, W, ws);
    hipLaunchKernelGGL(final_kernel, dim3(NB), dim3(256), 0, stream, ws, out);
}